// Round 1
// baseline (17.670 us; speedup 1.0000x reference)
//
#include <hip/hip_runtime.h>
#include <math.h>

// RoleLearner forward: noisy-OR direct + pairwise-indirect + contrast logits.
// T=2048 rows, C=64 concepts, E=16 experts (C,E hard-coded for unrolling).
//
// Key transform: sum_{i,j} log(1 - a_i a_j) = -sum_k S_k^2 / k with
// S_k = sum_i a_i^k (valid since a <= 0.5 -> EPS clip never binds there).
// K=16 terms -> truncation error ~1e-8. D-term and diag-term use real logs
// with the reference's EPS clip replicated exactly (1-D can cross 1e-6).

#define EPSF 1e-6f

constexpr int C_ = 64;
constexpr int E_ = 16;
constexpr int ROWS = 4;      // t-rows per block -> block = 64 threads, grid = T/4 = 512
constexpr int KTERMS = 16;   // power-series terms; err <= 4096*0.25^17/17 ~ 1.4e-8

__device__ __forceinline__ float logit_clip(float x) {
    // matches reference _logit: clip to [EPS, 1-EPS], log(x) - log1p(-x)
    x = fminf(fmaxf(x, EPSF), 1.0f - EPSF);
    return __logf(x) - __logf(1.0f - x);
}

__global__ __launch_bounds__(ROWS * E_) void role_fwd(
    const float* __restrict__ pbar,      // [T, C]
    const float* __restrict__ rho_dir,   // [C, E]
    const float* __restrict__ rho_ind,   // [C, E]
    const float* __restrict__ gamma_dir, // [E]
    const float* __restrict__ gamma_ind, // [E]
    const float* __restrict__ gamma_ctr, // [E]
    const float* __restrict__ bias,      // [E]
    float* __restrict__ out,             // [T, E]
    int T)
{
    // stride C_+1 = 65: bank(lt*65+c) = (lt+c)%32 -> the 4 lt-groups hit 4
    // distinct banks while each group's 16 e-lanes broadcast one address.
    __shared__ float sp[ROWS][C_ + 1];

    const int tid = threadIdx.x;
    const int t0  = blockIdx.x * ROWS;

    // cooperative stage of ROWS x C p-values (4 elems/thread, coalesced)
    for (int idx = tid; idx < ROWS * C_; idx += ROWS * E_) {
        int lt = idx >> 6;           // idx / C_
        int c  = idx & (C_ - 1);
        int t  = t0 + lt;
        sp[lt][c] = (t < T) ? pbar[t * C_ + c] : 0.0f;
    }
    __syncthreads();

    const int e  = tid & (E_ - 1);
    const int lt = tid >> 4;
    const int t  = t0 + lt;
    if (t >= T) return;

    float S[KTERMS];
#pragma unroll
    for (int k = 0; k < KTERMS; ++k) S[k] = 0.0f;
    float sd    = 0.0f;   // sum_c log(clip(1 - rd*p, EPS))  = log(1-D)
    float sdiag = 0.0f;   // sum_c log(clip(1 - a^2, EPS))   = log_diag

    for (int c = 0; c < C_; ++c) {
        float p  = sp[lt][c];
        float rd = fminf(fmaxf(rho_dir[c * E_ + e], 0.0f), 1.0f);
        float ri = fminf(fmaxf(rho_ind[c * E_ + e], 0.0f), 1.0f);

        float b = p * rd;
        sd += __logf(fmaxf(1.0f - b, EPSF));

        float a = p * ri;
        sdiag += __logf(fmaxf(1.0f - a * a, EPSF));

        float tp = a;                       // a^1
#pragma unroll
        for (int k = 0; k < KTERMS; ++k) {  // S[k] accumulates sum_c a^(k+1)
            S[k] += tp;
            tp *= a;
        }
    }

    // log_all = sum_{i,j} log(1 - a_i a_j) = -sum_k S_k^2 / k
    float log_all = 0.0f;
#pragma unroll
    for (int k = 0; k < KTERMS; ++k)
        log_all -= S[k] * S[k] * (1.0f / (float)(k + 1));

    float ilog = 0.5f * (log_all - sdiag);  // = log(1 - I)

    float D   = 1.0f - __expf(sd);
    float I   = 1.0f - __expf(ilog);
    float Ctr = __expf(sd) * __expf(ilog);  // (1-D)*(1-I)

    float logits = gamma_dir[e] * logit_clip(D)
                 + gamma_ind[e] * logit_clip(I)
                 + gamma_ctr[e] * logit_clip(Ctr)
                 + bias[e];

    out[t * E_ + e] = 1.0f / (1.0f + __expf(-logits));
}

extern "C" void kernel_launch(void* const* d_in, const int* in_sizes, int n_in,
                              void* d_out, int out_size, void* d_ws, size_t ws_size,
                              hipStream_t stream) {
    const float* pbar      = (const float*)d_in[0];
    const float* rho_dir   = (const float*)d_in[1];
    const float* rho_ind   = (const float*)d_in[2];
    // d_in[3] = rho_ctr, unused in forward
    const float* gamma_dir = (const float*)d_in[4];
    const float* gamma_ind = (const float*)d_in[5];
    const float* gamma_ctr = (const float*)d_in[6];
    const float* bias      = (const float*)d_in[7];
    float* out = (float*)d_out;

    const int T = in_sizes[0] / C_;   // 131072 / 64 = 2048
    const int grid = (T + ROWS - 1) / ROWS;

    role_fwd<<<grid, ROWS * E_, 0, stream>>>(
        pbar, rho_dir, rho_ind, gamma_dir, gamma_ind, gamma_ctr, bias, out, T);
}

// Round 2
// 10.376 us; speedup vs baseline: 1.7030x; 1.7030x over previous
//
#include <hip/hip_runtime.h>
#include <math.h>

// RoleLearner forward: noisy-OR direct + pairwise-indirect + contrast logits.
// T=2048, C=64, E=16 (C,E hard-coded for unrolling).
//
// Pairwise term via power series: sum_{i,j} log(1 - a_i a_j) = -sum_k S_k^2/k,
// S_k = sum_i a_i^k. Valid: a = clip(rho_ind)*p <= 0.5 -> EPS clip never binds
// on pair terms; K=10 truncation error <= 4096*0.25^11/11 ~ 9e-5 (log-space),
// invisible vs the 2e-2 absmax threshold (round-1 with K=16 scored absmax 0.0).
//
// Parallelism: 4-way C-split per (t,e) cell; partial sums reduced with
// __shfl_xor across lanes 16/32 (all 4 split-lanes of a cell live in one wave).
// Layout: tid = lt*64 + split*16 + e   (lt = local t-row, 4 rows/block).

#define EPSF 1e-6f

constexpr int C_     = 64;
constexpr int E_     = 16;
constexpr int ROWS   = 4;                  // t-rows per block
constexpr int SPLIT  = 4;                  // c-chunks per (t,e)
constexpr int CSUB   = C_ / SPLIT;         // 16 c's per thread
constexpr int KTERMS = 10;                 // power-series terms
constexpr int BLK    = ROWS * SPLIT * E_;  // 256 threads

__device__ __forceinline__ float logit_clip(float x) {
    // matches reference _logit: clip to [EPS, 1-EPS], log(x) - log1p(-x)
    x = fminf(fmaxf(x, EPSF), 1.0f - EPSF);
    return __logf(x) - __logf(1.0f - x);
}

__global__ __launch_bounds__(BLK) void role_fwd(
    const float* __restrict__ pbar,      // [T, C]
    const float* __restrict__ rho_dir,   // [C, E]
    const float* __restrict__ rho_ind,   // [C, E]
    const float* __restrict__ gamma_dir, // [E]
    const float* __restrict__ gamma_ind, // [E]
    const float* __restrict__ gamma_ctr, // [E]
    const float* __restrict__ bias,      // [E]
    float* __restrict__ out,             // [T, E]
    int T)
{
    __shared__ float sp[ROWS][C_];        // 2-way bank alias on read (free)
    // [C][E_+1]: pad makes the 4 split-groups alias only 2-way per bank (free)
    __shared__ float rd_s[C_][E_ + 1];
    __shared__ float ri_s[C_][E_ + 1];

    const int tid = threadIdx.x;
    const int t0  = blockIdx.x * ROWS;

    // stage p: 256 floats, one coalesced load
    {
        int lt = tid >> 6, c = tid & (C_ - 1);
        int t  = t0 + lt;
        sp[lt][c] = (t < T) ? pbar[t * C_ + c] : 0.0f;
    }
    // stage rho with clip pre-applied (coalesced, 4 elems/thread/array)
    for (int i = tid; i < C_ * E_; i += BLK) {
        int c = i >> 4, e = i & (E_ - 1);
        rd_s[c][e] = fminf(fmaxf(rho_dir[i], 0.0f), 1.0f);
        ri_s[c][e] = fminf(fmaxf(rho_ind[i], 0.0f), 1.0f);
    }
    __syncthreads();

    const int e     = tid & (E_ - 1);
    const int split = (tid >> 4) & (SPLIT - 1);
    const int lt    = tid >> 6;
    const int t     = t0 + lt;

    float S[KTERMS];
#pragma unroll
    for (int k = 0; k < KTERMS; ++k) S[k] = 0.0f;
    float sd    = 0.0f;   // partial sum_c log(clip(1 - rd*p, EPS))
    float sdiag = 0.0f;   // partial sum_c log(clip(1 - a^2, EPS))

    const int cbase = split * CSUB;
#pragma unroll
    for (int cc = 0; cc < CSUB; ++cc) {
        const int c = cbase + cc;
        float p  = sp[lt][c];
        float rd = rd_s[c][e];
        float ri = ri_s[c][e];

        float omb = fmaxf(fmaf(-p, rd, 1.0f), EPSF);   // 1 - p*rd
        sd += __logf(omb);

        float a    = p * ri;
        float oma2 = fmaxf(fmaf(-a, a, 1.0f), EPSF);   // 1 - a^2
        sdiag += __logf(oma2);

        float tp = a;
#pragma unroll
        for (int k = 0; k < KTERMS; ++k) { S[k] += tp; tp *= a; }
    }

    // reduce the 12 partials across the 4 split-lanes (xor 16, then 32)
#pragma unroll
    for (int m = E_; m < 64; m <<= 1) {
        sd    += __shfl_xor(sd, m);
        sdiag += __shfl_xor(sdiag, m);
#pragma unroll
        for (int k = 0; k < KTERMS; ++k) S[k] += __shfl_xor(S[k], m);
    }

    // log_all = -sum_k S_k^2 / k
    float log_all = 0.0f;
#pragma unroll
    for (int k = 0; k < KTERMS; ++k)
        log_all -= S[k] * S[k] * (1.0f / (float)(k + 1));

    float ilog = 0.5f * (log_all - sdiag);  // log(1 - I)

    float D   = 1.0f - __expf(sd);
    float I   = 1.0f - __expf(ilog);
    float Ctr = __expf(sd) * __expf(ilog);  // (1-D)*(1-I)

    float logits = gamma_dir[e] * logit_clip(D)
                 + gamma_ind[e] * logit_clip(I)
                 + gamma_ctr[e] * logit_clip(Ctr)
                 + bias[e];

    if (split == 0 && t < T)
        out[t * E_ + e] = 1.0f / (1.0f + __expf(-logits));
}

extern "C" void kernel_launch(void* const* d_in, const int* in_sizes, int n_in,
                              void* d_out, int out_size, void* d_ws, size_t ws_size,
                              hipStream_t stream) {
    const float* pbar      = (const float*)d_in[0];
    const float* rho_dir   = (const float*)d_in[1];
    const float* rho_ind   = (const float*)d_in[2];
    // d_in[3] = rho_ctr, unused in forward
    const float* gamma_dir = (const float*)d_in[4];
    const float* gamma_ind = (const float*)d_in[5];
    const float* gamma_ctr = (const float*)d_in[6];
    const float* bias      = (const float*)d_in[7];
    float* out = (float*)d_out;

    const int T = in_sizes[0] / C_;   // 131072 / 64 = 2048
    const int grid = (T + ROWS - 1) / ROWS;

    role_fwd<<<grid, BLK, 0, stream>>>(
        pbar, rho_dir, rho_ind, gamma_dir, gamma_ind, gamma_ctr, bias, out, T);
}

// Round 3
// 9.767 us; speedup vs baseline: 1.8092x; 1.0623x over previous
//
#include <hip/hip_runtime.h>
#include <math.h>

// RoleLearner forward: noisy-OR direct + pairwise-indirect + contrast logits.
// T=2048, C=64, E=16 (C,E hard-coded for unrolling).
//
// Pairwise term via power series: sum_{i,j} log(1 - a_i a_j) = -sum_k S_k^2/k,
// S_k = sum_i a_i^k  (a = clip(rho_ind)*p <= 1; series converges, EPS clip on
// pair terms never binds for a_i*a_j <= 0.25). KTERMS=8: worst-case tail
// <= 1.9e-3 log-space -> <=1e-3 on sigmoid output, vs 2e-2 threshold.
//
// log-sums replaced by clamped products: sd = log(prod(clip(1-p*rd, EPS)))
// -> exp(sd) == prod_d directly, so D and Ctr need no transcendentals at all.
// Partial products >= EPS^16 can't underflow for real data (>= 0.5^16); in
// saturated regimes both ref and this kernel round to the same fp32 values.
//
// Parallelism: 4-way C-split per (t,e); partials reduced via __shfl_xor 16/32
// (mult-reduce for products, add-reduce for S_k). tid = lt*64 + split*16 + e.

#define EPSF 1e-6f

constexpr int C_     = 64;
constexpr int E_     = 16;
constexpr int ROWS   = 4;                  // t-rows per block
constexpr int SPLIT  = 4;                  // c-chunks per (t,e)
constexpr int CSUB   = C_ / SPLIT;         // 16 c's per thread
constexpr int KTERMS = 8;                  // power-series terms
constexpr int BLK    = ROWS * SPLIT * E_;  // 256 threads

__device__ __forceinline__ float logit_clip(float x) {
    // matches reference _logit: clip to [EPS, 1-EPS], log(x) - log1p(-x)
    x = fminf(fmaxf(x, EPSF), 1.0f - EPSF);
    return __logf(x) - __logf(1.0f - x);
}

__global__ __launch_bounds__(BLK) void role_fwd(
    const float* __restrict__ pbar,      // [T, C]
    const float* __restrict__ rho_dir,   // [C, E]
    const float* __restrict__ rho_ind,   // [C, E]
    const float* __restrict__ gamma_dir, // [E]
    const float* __restrict__ gamma_ind, // [E]
    const float* __restrict__ gamma_ctr, // [E]
    const float* __restrict__ bias,      // [E]
    float* __restrict__ out,             // [T, E]
    int T)
{
    __shared__ float sp[ROWS][C_];        // read alias 2-way max (free)
    // stride 17 (odd): the 4 split-groups (c += 16) land on 2 banks -> 2-way (free)
    __shared__ float rd_s[C_][E_ + 1];
    __shared__ float ri_s[C_][E_ + 1];

    const int tid = threadIdx.x;
    const int t0  = blockIdx.x * ROWS;

    // stage p: 256 floats, coalesced
    {
        int plt = tid >> 6, pc = tid & (C_ - 1);
        int pt  = t0 + plt;
        sp[plt][pc] = (pt < T) ? pbar[pt * C_ + pc] : 0.0f;
    }
    // stage rho as float4 (1024 floats each), clip once, scalar LDS writes
    {
        float4 vd = reinterpret_cast<const float4*>(rho_dir)[tid];
        float4 vi = reinterpret_cast<const float4*>(rho_ind)[tid];
        int c  = tid >> 2;
        int e0 = (tid & 3) * 4;
        rd_s[c][e0 + 0] = fminf(fmaxf(vd.x, 0.0f), 1.0f);
        rd_s[c][e0 + 1] = fminf(fmaxf(vd.y, 0.0f), 1.0f);
        rd_s[c][e0 + 2] = fminf(fmaxf(vd.z, 0.0f), 1.0f);
        rd_s[c][e0 + 3] = fminf(fmaxf(vd.w, 0.0f), 1.0f);
        ri_s[c][e0 + 0] = fminf(fmaxf(vi.x, 0.0f), 1.0f);
        ri_s[c][e0 + 1] = fminf(fmaxf(vi.y, 0.0f), 1.0f);
        ri_s[c][e0 + 2] = fminf(fmaxf(vi.z, 0.0f), 1.0f);
        ri_s[c][e0 + 3] = fminf(fmaxf(vi.w, 0.0f), 1.0f);
    }
    __syncthreads();

    const int e     = tid & (E_ - 1);
    const int split = (tid >> 4) & (SPLIT - 1);
    const int lt    = tid >> 6;
    const int t     = t0 + lt;

    // hoist tail-phase loads so latency overlaps the main loop
    const float gd = gamma_dir[e], gi = gamma_ind[e], gc = gamma_ctr[e], bs = bias[e];

    float S1 = 0.f, S2 = 0.f, S3 = 0.f, S4 = 0.f,
          S5 = 0.f, S6 = 0.f, S7 = 0.f, S8 = 0.f;
    float prod_d = 1.0f;   // prod_c clip(1 - rd*p, EPS)   -> exp(sd)
    float prod_i = 1.0f;   // prod_c clip(1 - a^2,  EPS)   -> exp(sdiag)

    const int cbase = split * CSUB;
#pragma unroll
    for (int cc = 0; cc < CSUB; ++cc) {
        const int c = cbase + cc;
        float p  = sp[lt][c];
        float rd = rd_s[c][e];
        float ri = ri_s[c][e];

        prod_d *= fmaxf(fmaf(-p, rd, 1.0f), EPSF);

        float a  = p * ri;
        float q  = a * a;
        prod_i *= fmaxf(1.0f - q, EPSF);

        float q2 = q * q;
        float q3 = q2 * q;
        float q4 = q2 * q2;
        S1 += a;             // a^1
        S2 += q;             // a^2
        S3 = fmaf(a, q, S3); // a^3
        S4 += q2;            // a^4
        S5 = fmaf(a, q2, S5);
        S6 += q3;
        S7 = fmaf(a, q3, S7);
        S8 += q4;
    }

    // reduce across the 4 split-lanes (xor 16, then 32)
#pragma unroll
    for (int m = E_; m < 64; m <<= 1) {
        prod_d *= __shfl_xor(prod_d, m);
        prod_i *= __shfl_xor(prod_i, m);
        S1 += __shfl_xor(S1, m);  S2 += __shfl_xor(S2, m);
        S3 += __shfl_xor(S3, m);  S4 += __shfl_xor(S4, m);
        S5 += __shfl_xor(S5, m);  S6 += __shfl_xor(S6, m);
        S7 += __shfl_xor(S7, m);  S8 += __shfl_xor(S8, m);
    }

    // pair_sum = sum_k S_k^2 / k  (= -log_all)
    float pair_sum = S1 * S1;
    pair_sum = fmaf(S2 * S2, 1.0f / 2.0f, pair_sum);
    pair_sum = fmaf(S3 * S3, 1.0f / 3.0f, pair_sum);
    pair_sum = fmaf(S4 * S4, 1.0f / 4.0f, pair_sum);
    pair_sum = fmaf(S5 * S5, 1.0f / 5.0f, pair_sum);
    pair_sum = fmaf(S6 * S6, 1.0f / 6.0f, pair_sum);
    pair_sum = fmaf(S7 * S7, 1.0f / 7.0f, pair_sum);
    pair_sum = fmaf(S8 * S8, 1.0f / 8.0f, pair_sum);

    // ilog = 0.5*(log_all - sdiag);  exp(sdiag) == prod_i
    float ilog = -0.5f * pair_sum - 0.5f * __logf(prod_i);
    float ei   = __expf(ilog);              // exp(log(1-I))

    float D   = 1.0f - prod_d;
    float I   = 1.0f - ei;
    float Ctr = prod_d * ei;                // (1-D)*(1-I)

    float logits = gd * logit_clip(D)
                 + gi * logit_clip(I)
                 + gc * logit_clip(Ctr)
                 + bs;

    if (split == 0 && t < T)
        out[t * E_ + e] = 1.0f / (1.0f + __expf(-logits));
}

extern "C" void kernel_launch(void* const* d_in, const int* in_sizes, int n_in,
                              void* d_out, int out_size, void* d_ws, size_t ws_size,
                              hipStream_t stream) {
    const float* pbar      = (const float*)d_in[0];
    const float* rho_dir   = (const float*)d_in[1];
    const float* rho_ind   = (const float*)d_in[2];
    // d_in[3] = rho_ctr, unused in forward
    const float* gamma_dir = (const float*)d_in[4];
    const float* gamma_ind = (const float*)d_in[5];
    const float* gamma_ctr = (const float*)d_in[6];
    const float* bias      = (const float*)d_in[7];
    float* out = (float*)d_out;

    const int T = in_sizes[0] / C_;   // 131072 / 64 = 2048
    const int grid = (T + ROWS - 1) / ROWS;

    role_fwd<<<grid, BLK, 0, stream>>>(
        pbar, rho_dir, rho_ind, gamma_dir, gamma_ind, gamma_ctr, bias, out, T);
}

// Round 4
// 9.389 us; speedup vs baseline: 1.8821x; 1.0403x over previous
//
#include <hip/hip_runtime.h>
#include <math.h>

// RoleLearner forward: noisy-OR direct + pairwise-indirect + contrast logits.
// T=2048, C=64, E=16 (C,E hard-coded for unrolling).
//
// Pairwise term via power series: sum_{i,j} log(1 - a_i a_j) = -sum_k S_k^2/k,
// S_k = sum_i a_i^k. KTERMS=8: worst-case tail <= 1.9e-3 in log-space ->
// <= 1e-3 on the sigmoid output, vs the 2e-2 absmax threshold (rounds 1-3
// scored absmax 0.0).
//
// log-sums are clamped products: prod_d = prod_c clip(1-p*rd, EPS) == exp(sd),
// so D and Ctr need no transcendentals; one __logf + __expf remain for I.
//
// No LDS, no barrier: pbar[t*64+c] is the SAME address across each 16-lane
// e-group (HW broadcast), rho[c*16+e] is a coalesced 64B run per group; both
// L1/L2-hot (rho reused by all blocks). Full unroll -> all loads issue up
// front, one latency wait instead of stage->barrier->ds_read round-trip.
//
// Parallelism: 4-way C-split per (t,e); partials reduced via __shfl_xor 16/32.
// tid = lt*64 + split*16 + e.

#define EPSF 1e-6f

constexpr int C_     = 64;
constexpr int E_     = 16;
constexpr int ROWS   = 4;                  // t-rows per block
constexpr int SPLIT  = 4;                  // c-chunks per (t,e)
constexpr int CSUB   = C_ / SPLIT;         // 16 c's per thread
constexpr int BLK    = ROWS * SPLIT * E_;  // 256 threads

__device__ __forceinline__ float logit_clip(float x) {
    // matches reference _logit: clip to [EPS, 1-EPS], log(x) - log1p(-x)
    x = fminf(fmaxf(x, EPSF), 1.0f - EPSF);
    return __logf(x) - __logf(1.0f - x);
}

__global__ __launch_bounds__(BLK) void role_fwd(
    const float* __restrict__ pbar,      // [T, C]
    const float* __restrict__ rho_dir,   // [C, E]
    const float* __restrict__ rho_ind,   // [C, E]
    const float* __restrict__ gamma_dir, // [E]
    const float* __restrict__ gamma_ind, // [E]
    const float* __restrict__ gamma_ctr, // [E]
    const float* __restrict__ bias,      // [E]
    float* __restrict__ out,             // [T, E]
    int T)
{
    const int tid   = threadIdx.x;
    const int e     = tid & (E_ - 1);
    const int split = (tid >> 4) & (SPLIT - 1);
    const int lt    = tid >> 6;
    const int t     = blockIdx.x * ROWS + lt;
    const bool live = (t < T);

    // hoist tail-phase loads so their latency overlaps the main loop
    const float gd = gamma_dir[e], gi = gamma_ind[e], gc = gamma_ctr[e], bs = bias[e];

    const int cbase = split * CSUB;
    const float* prow = pbar + (live ? t : 0) * C_ + cbase;
    const float* rdp  = rho_dir + cbase * E_ + e;
    const float* rip  = rho_ind + cbase * E_ + e;

    float S1 = 0.f, S2 = 0.f, S3 = 0.f, S4 = 0.f,
          S5 = 0.f, S6 = 0.f, S7 = 0.f, S8 = 0.f;
    float prod_d = 1.0f;   // prod_c clip(1 - rd*p, EPS)  == exp(sd)
    float prod_i = 1.0f;   // prod_c clip(1 - a^2,  EPS)  == exp(sdiag)

#pragma unroll
    for (int cc = 0; cc < CSUB; ++cc) {
        float p  = prow[cc];
        float rd = fminf(fmaxf(rdp[cc * E_], 0.0f), 1.0f);
        float ri = fminf(fmaxf(rip[cc * E_], 0.0f), 1.0f);

        prod_d *= fmaxf(fmaf(-p, rd, 1.0f), EPSF);

        float a  = p * ri;
        float q  = a * a;
        prod_i *= fmaxf(1.0f - q, EPSF);

        float q2 = q * q;
        float q3 = q2 * q;
        float q4 = q2 * q2;
        S1 += a;
        S2 += q;
        S3 = fmaf(a, q, S3);
        S4 += q2;
        S5 = fmaf(a, q2, S5);
        S6 += q3;
        S7 = fmaf(a, q3, S7);
        S8 += q4;
    }

    // reduce the partials across the 4 split-lanes (xor 16, then 32)
#pragma unroll
    for (int m = E_; m < 64; m <<= 1) {
        prod_d *= __shfl_xor(prod_d, m);
        prod_i *= __shfl_xor(prod_i, m);
        S1 += __shfl_xor(S1, m);  S2 += __shfl_xor(S2, m);
        S3 += __shfl_xor(S3, m);  S4 += __shfl_xor(S4, m);
        S5 += __shfl_xor(S5, m);  S6 += __shfl_xor(S6, m);
        S7 += __shfl_xor(S7, m);  S8 += __shfl_xor(S8, m);
    }

    // pair_sum = sum_k S_k^2 / k  (= -log_all)
    float pair_sum = S1 * S1;
    pair_sum = fmaf(S2 * S2, 1.0f / 2.0f, pair_sum);
    pair_sum = fmaf(S3 * S3, 1.0f / 3.0f, pair_sum);
    pair_sum = fmaf(S4 * S4, 1.0f / 4.0f, pair_sum);
    pair_sum = fmaf(S5 * S5, 1.0f / 5.0f, pair_sum);
    pair_sum = fmaf(S6 * S6, 1.0f / 6.0f, pair_sum);
    pair_sum = fmaf(S7 * S7, 1.0f / 7.0f, pair_sum);
    pair_sum = fmaf(S8 * S8, 1.0f / 8.0f, pair_sum);

    // ilog = 0.5*(log_all - sdiag);  exp(sdiag) == prod_i
    float ilog = -0.5f * pair_sum - 0.5f * __logf(prod_i);
    float ei   = __expf(ilog);              // exp(log(1-I))

    float D   = 1.0f - prod_d;
    float I   = 1.0f - ei;
    float Ctr = prod_d * ei;                // (1-D)*(1-I)

    float logits = gd * logit_clip(D)
                 + gi * logit_clip(I)
                 + gc * logit_clip(Ctr)
                 + bs;

    if (split == 0 && live)
        out[t * E_ + e] = 1.0f / (1.0f + __expf(-logits));
}

extern "C" void kernel_launch(void* const* d_in, const int* in_sizes, int n_in,
                              void* d_out, int out_size, void* d_ws, size_t ws_size,
                              hipStream_t stream) {
    const float* pbar      = (const float*)d_in[0];
    const float* rho_dir   = (const float*)d_in[1];
    const float* rho_ind   = (const float*)d_in[2];
    // d_in[3] = rho_ctr, unused in forward
    const float* gamma_dir = (const float*)d_in[4];
    const float* gamma_ind = (const float*)d_in[5];
    const float* gamma_ctr = (const float*)d_in[6];
    const float* bias      = (const float*)d_in[7];
    float* out = (float*)d_out;

    const int T = in_sizes[0] / C_;   // 131072 / 64 = 2048
    const int grid = (T + ROWS - 1) / ROWS;

    role_fwd<<<grid, BLK, 0, stream>>>(
        pbar, rho_dir, rho_ind, gamma_dir, gamma_ind, gamma_ctr, bias, out, T);
}